// Round 1
// baseline (1154.325 us; speedup 1.0000x reference)
//
#include <hip/hip_runtime.h>
#include <math.h>

// PatchNCE loss, 4 layers, B=8, 64 samples x 8 neighbors = S=512 per batch.
// Layout: per layer l, d_in[7l+..] = fq, fk, sid, w1, b1, w2, b2; output scalar f32.
// Pipeline per layer/side: gather -> ft (4096 x C) -> gemm1(relu) -> y1 (4096 x C)
//   -> gemm2+rownorm -> F (4096 x C/4) ; then NCE(Fq,Fk) atomicAdds into d_out[0].
// ws usage: ft(8MB) + y1(8MB) + Fq(2MB) + Fk(2MB) = 20 MB.

#define BATCH 8
#define SS    512
#define MM    4096   // BATCH * SS

__global__ void zero_kernel(float* __restrict__ out) { out[0] = 0.0f; }

// ---------------- gather: ft[row][ch] = feat[b,ch,h,w] - feat[b,ch,hc,wc] ----
__global__ void gather_kernel(const float* __restrict__ feat,
                              const int* __restrict__ sid,
                              float* __restrict__ ft, int C, int H) {
  const int row = blockIdx.x;              // b*512 + s*8 + n
  const int b = row >> 9;
  const int s = (row >> 3) & 63;
  const int n = row & 7;
  const int idx = n < 4 ? n : n + 1;       // skip center of 3x3
  const int dh = idx / 3, dw = idx % 3;
  const int sh = sid[2 * s], sw = sid[2 * s + 1];
  const int HW = H * H;
  const float* fb = feat + (size_t)b * C * HW;
  const int o1 = (sh + dh) * H + (sw + dw);
  const int o2 = (sh + 1) * H + (sw + 1);
  for (int ch = threadIdx.x; ch < C; ch += blockDim.x) {
    ft[row * C + ch] = fb[ch * HW + o1] - fb[ch * HW + o2];
  }
}

// ---------------- gemm1: Y = relu(A @ W^T + b), A: M x K, W: N x K, N==K==C --
// 128x64 block tile, 8x4 per thread, BK=16, NT layout (K contiguous both sides)
__global__ __launch_bounds__(256) void gemm1_relu_kernel(
    const float* __restrict__ A, const float* __restrict__ W,
    const float* __restrict__ bias, float* __restrict__ Y, int K) {
  const int N = K;
  __shared__ float As[16][128];
  __shared__ float Bs[16][64];
  const int tid = threadIdx.x;
  const int tx = tid & 15;        // 4 cols each
  const int ty = tid >> 4;        // 8 rows each
  const int m0 = blockIdx.x * 128;
  const int n0 = blockIdx.y * 64;
  float acc[8][4];
#pragma unroll
  for (int i = 0; i < 8; ++i)
#pragma unroll
    for (int j = 0; j < 4; ++j) acc[i][j] = 0.f;

  const int ar = tid >> 1;             // 0..127
  const int ac = (tid & 1) * 8;        // 0 or 8
  const int br = tid >> 2;             // 0..63
  const int bc = (tid & 3) * 4;        // 0,4,8,12

  for (int k0 = 0; k0 < K; k0 += 16) {
    float4 a0 = *(const float4*)(A + (m0 + ar) * K + k0 + ac);
    float4 a1 = *(const float4*)(A + (m0 + ar) * K + k0 + ac + 4);
    float4 b0 = *(const float4*)(W + (n0 + br) * K + k0 + bc);
    As[ac + 0][ar] = a0.x; As[ac + 1][ar] = a0.y;
    As[ac + 2][ar] = a0.z; As[ac + 3][ar] = a0.w;
    As[ac + 4][ar] = a1.x; As[ac + 5][ar] = a1.y;
    As[ac + 6][ar] = a1.z; As[ac + 7][ar] = a1.w;
    Bs[bc + 0][br] = b0.x; Bs[bc + 1][br] = b0.y;
    Bs[bc + 2][br] = b0.z; Bs[bc + 3][br] = b0.w;
    __syncthreads();
#pragma unroll
    for (int kk = 0; kk < 16; ++kk) {
      float av[8], bv[4];
#pragma unroll
      for (int i = 0; i < 8; ++i) av[i] = As[kk][ty * 8 + i];
#pragma unroll
      for (int j = 0; j < 4; ++j) bv[j] = Bs[kk][tx * 4 + j];
#pragma unroll
      for (int i = 0; i < 8; ++i)
#pragma unroll
        for (int j = 0; j < 4; ++j) acc[i][j] += av[i] * bv[j];
    }
    __syncthreads();
  }
  const float4 bb = *(const float4*)(bias + n0 + tx * 4);
#pragma unroll
  for (int i = 0; i < 8; ++i) {
    const int m = m0 + ty * 8 + i;
    float4 v;
    v.x = fmaxf(acc[i][0] + bb.x, 0.f);
    v.y = fmaxf(acc[i][1] + bb.y, 0.f);
    v.z = fmaxf(acc[i][2] + bb.z, 0.f);
    v.w = fmaxf(acc[i][3] + bb.w, 0.f);
    *(float4*)(Y + m * N + n0 + tx * 4) = v;
  }
}

// ------- gemm2 + L2 row-normalize: F[m][j] = (Y1@W2^T + b2) / (||row||+1e-7) -
// 16 rows per block; Y1 rows staged in LDS; W2 rows broadcast-read from L1/L2.
__global__ __launch_bounds__(256) void gemm2_norm_kernel(
    const float* __restrict__ Y1, const float* __restrict__ W2,
    const float* __restrict__ b2, float* __restrict__ F, int K, int C4) {
  __shared__ float Ys[16 * 516];        // stride K+4 (multiple of 4 -> float4 ok)
  __shared__ float ys2[16][129];
  __shared__ float scl[16];
  const int tid = threadIdx.x;
  const int row0 = blockIdx.x * 16;
  const int ldy = K + 4;
  for (int e = tid * 4; e < 16 * K; e += 1024) {
    int r = e / K, k = e - r * K;
    *(float4*)(&Ys[r * ldy + k]) = *(const float4*)(Y1 + (row0 + r) * K + k);
  }
  __syncthreads();
  const int r = tid & 15;
  const int jg = tid >> 4;
  const float* ysr = &Ys[r * ldy];
  for (int j0 = jg * 4; j0 < C4; j0 += 64) {
    float a0 = b2[j0], a1 = b2[j0 + 1], a2 = b2[j0 + 2], a3 = b2[j0 + 3];
    const float* w0 = W2 + (j0 + 0) * K;
    const float* w1 = W2 + (j0 + 1) * K;
    const float* w2 = W2 + (j0 + 2) * K;
    const float* w3 = W2 + (j0 + 3) * K;
    for (int k = 0; k < K; k += 4) {
      float4 y = *(const float4*)(ysr + k);
      float4 v0 = *(const float4*)(w0 + k);
      float4 v1 = *(const float4*)(w1 + k);
      float4 v2 = *(const float4*)(w2 + k);
      float4 v3 = *(const float4*)(w3 + k);
      a0 += y.x * v0.x + y.y * v0.y + y.z * v0.z + y.w * v0.w;
      a1 += y.x * v1.x + y.y * v1.y + y.z * v1.z + y.w * v1.w;
      a2 += y.x * v2.x + y.y * v2.y + y.z * v2.z + y.w * v2.w;
      a3 += y.x * v3.x + y.y * v3.y + y.z * v3.z + y.w * v3.w;
    }
    ys2[r][j0 + 0] = a0; ys2[r][j0 + 1] = a1;
    ys2[r][j0 + 2] = a2; ys2[r][j0 + 3] = a3;
  }
  __syncthreads();
  if (tid < 16) {
    float sum = 0.f;
    for (int j = 0; j < C4; ++j) { float v = ys2[tid][j]; sum += v * v; }
    scl[tid] = 1.f / (sqrtf(sum) + 1e-7f);
  }
  __syncthreads();
  for (int e = tid; e < 16 * C4; e += 256) {
    int rr = e / C4, j = e - rr * C4;
    F[(row0 + rr) * C4 + j] = ys2[rr][j] * scl[rr];
  }
}

// ---------------- NCE: per (b, 32-row s tile); fixed max-shift logsumexp -----
// logits bounded by 1/tau (unit-norm features) -> shift by invtau, no overflow.
__global__ __launch_bounds__(256) void nce_kernel(
    const float* __restrict__ Fq, const float* __restrict__ Fk,
    float* __restrict__ loss, int C4, float invtau, float scale) {
  __shared__ float FqS[32][129];
  __shared__ float part[8][32];
  __shared__ float posS[32];
  __shared__ float red[32];
  const int b = blockIdx.y;
  const int s0 = blockIdx.x * 32;
  const int tid = threadIdx.x;
  for (int e = tid; e < 32 * C4; e += 256) {
    int r = e / C4, k = e - r * C4;
    FqS[r][k] = Fq[(b * SS + s0 + r) * C4 + k];
  }
  __syncthreads();
  const int sl = tid & 31;
  const int g = tid >> 5;          // 8 groups, each covers t = g, g+8, ...
  const int s = s0 + sl;
  const float* fqr = FqS[sl];
  float partial = 0.f;
  float posv = 0.f;
  for (int t = g; t < SS; t += 8) {
    const float* fk = Fk + (b * SS + t) * C4;
    float d = 0.f;
#pragma unroll 4
    for (int k = 0; k < C4; ++k) d += fqr[k] * fk[k];
    if (t == s) posv = d;
    else partial += __expf(d * invtau - invtau);
  }
  part[g][sl] = partial;
  if ((s & 7) == g) posS[sl] = posv;
  __syncthreads();
  if (tid < 32) {
    float tot = 0.f;
#pragma unroll
    for (int gg = 0; gg < 8; ++gg) tot += part[gg][tid];
    const float p = posS[tid];
    tot += __expf(p * invtau - invtau);
    red[tid] = (logf(tot) + invtau) - p * invtau;
  }
  __syncthreads();
  if (tid == 0) {
    float sum = 0.f;
    for (int i = 0; i < 32; ++i) sum += red[i];
    atomicAdd(loss, sum * scale);
  }
}

extern "C" void kernel_launch(void* const* d_in, const int* in_sizes, int n_in,
                              void* d_out, int out_size, void* d_ws, size_t ws_size,
                              hipStream_t stream) {
  const int Cs[4] = {64, 128, 256, 512};
  const int Hs[4] = {256, 128, 64, 32};
  float* ws = (float*)d_ws;
  float* ft = ws;                          // 4096*512
  float* y1 = ws + MM * 512;               // 4096*512
  float* Fq = ws + 2 * MM * 512;           // 4096*128
  float* Fk = Fq + MM * 128;
  float* out = (float*)d_out;

  hipLaunchKernelGGL(zero_kernel, dim3(1), dim3(1), 0, stream, out);

  for (int l = 0; l < 4; ++l) {
    const float* fq = (const float*)d_in[7 * l + 0];
    const float* fk = (const float*)d_in[7 * l + 1];
    const int* sid  = (const int*)d_in[7 * l + 2];
    const float* w1 = (const float*)d_in[7 * l + 3];
    const float* b1 = (const float*)d_in[7 * l + 4];
    const float* w2 = (const float*)d_in[7 * l + 5];
    const float* b2 = (const float*)d_in[7 * l + 6];
    const int C = Cs[l], H = Hs[l], C4 = C / 4;
    const int gblk = C < 256 ? C : 256;

    for (int side = 0; side < 2; ++side) {
      const float* feat = side ? fk : fq;
      float* F = side ? Fk : Fq;
      hipLaunchKernelGGL(gather_kernel, dim3(MM), dim3(gblk), 0, stream,
                         feat, sid, ft, C, H);
      hipLaunchKernelGGL(gemm1_relu_kernel, dim3(MM / 128, C / 64), dim3(256),
                         0, stream, ft, w1, b1, y1, C);
      hipLaunchKernelGGL(gemm2_norm_kernel, dim3(MM / 16), dim3(256), 0, stream,
                         y1, w2, b2, F, C, C4);
    }
    hipLaunchKernelGGL(nce_kernel, dim3(SS / 32, BATCH), dim3(256), 0, stream,
                       Fq, Fk, out, C4, 1.0f / 0.07f, 1.0f / (float)MM);
  }
}

// Round 2
// 848.624 us; speedup vs baseline: 1.3602x; 1.3602x over previous
//
#include <hip/hip_runtime.h>
#include <math.h>

// PatchNCE loss, 4 layers, B=8, 64 samples x 8 neighbors = S=512 per batch.
// Per layer l, d_in[7l+..] = fq, fk, sid, w1, b1, w2, b2; output scalar f32.
// Pipeline per layer/side: gather -> ft (4096 x C) -> gemm1(relu) -> y1
//   -> gemm2+rownorm -> F (4096 x C/4); NCE = tiled Gram GEMM + fused exp
//   accumulating per-row expsums, then a finalize reduction into d_out[0].

#define BATCH 8
#define SS    512
#define MM    4096   // BATCH * SS

__global__ void zero_kernel(float* __restrict__ out) { out[0] = 0.0f; }

__global__ void zero_rowsum_kernel(float* __restrict__ rs) {
  int i = blockIdx.x * 256 + threadIdx.x;
  if (i < MM) rs[i] = 0.0f;
}

// ---------------- gather: ft[row][ch] = feat[b,ch,h,w] - feat[b,ch,hc,wc] ----
__global__ void gather_kernel(const float* __restrict__ feat,
                              const int* __restrict__ sid,
                              float* __restrict__ ft, int C, int H) {
  const int row = blockIdx.x;              // b*512 + s*8 + n
  const int b = row >> 9;
  const int s = (row >> 3) & 63;
  const int n = row & 7;
  const int idx = n < 4 ? n : n + 1;       // skip center of 3x3
  const int dh = idx / 3, dw = idx % 3;
  const int sh = sid[2 * s], sw = sid[2 * s + 1];
  const int HW = H * H;
  const float* fb = feat + (size_t)b * C * HW;
  const int o1 = (sh + dh) * H + (sw + dw);
  const int o2 = (sh + 1) * H + (sw + 1);
  for (int ch = threadIdx.x; ch < C; ch += blockDim.x) {
    ft[row * C + ch] = fb[ch * HW + o1] - fb[ch * HW + o2];
  }
}

// ---------------- gemm1: Y = relu(A @ W^T + b), A: M x K, W: N x K, N==K==C --
__global__ __launch_bounds__(256) void gemm1_relu_kernel(
    const float* __restrict__ A, const float* __restrict__ W,
    const float* __restrict__ bias, float* __restrict__ Y, int K) {
  const int N = K;
  __shared__ float As[16][128];
  __shared__ float Bs[16][64];
  const int tid = threadIdx.x;
  const int tx = tid & 15;
  const int ty = tid >> 4;
  const int m0 = blockIdx.x * 128;
  const int n0 = blockIdx.y * 64;
  float acc[8][4];
#pragma unroll
  for (int i = 0; i < 8; ++i)
#pragma unroll
    for (int j = 0; j < 4; ++j) acc[i][j] = 0.f;

  const int ar = tid >> 1;
  const int ac = (tid & 1) * 8;
  const int br = tid >> 2;
  const int bc = (tid & 3) * 4;

  for (int k0 = 0; k0 < K; k0 += 16) {
    float4 a0 = *(const float4*)(A + (m0 + ar) * K + k0 + ac);
    float4 a1 = *(const float4*)(A + (m0 + ar) * K + k0 + ac + 4);
    float4 b0 = *(const float4*)(W + (n0 + br) * K + k0 + bc);
    As[ac + 0][ar] = a0.x; As[ac + 1][ar] = a0.y;
    As[ac + 2][ar] = a0.z; As[ac + 3][ar] = a0.w;
    As[ac + 4][ar] = a1.x; As[ac + 5][ar] = a1.y;
    As[ac + 6][ar] = a1.z; As[ac + 7][ar] = a1.w;
    Bs[bc + 0][br] = b0.x; Bs[bc + 1][br] = b0.y;
    Bs[bc + 2][br] = b0.z; Bs[bc + 3][br] = b0.w;
    __syncthreads();
#pragma unroll
    for (int kk = 0; kk < 16; ++kk) {
      float av[8], bv[4];
#pragma unroll
      for (int i = 0; i < 8; ++i) av[i] = As[kk][ty * 8 + i];
#pragma unroll
      for (int j = 0; j < 4; ++j) bv[j] = Bs[kk][tx * 4 + j];
#pragma unroll
      for (int i = 0; i < 8; ++i)
#pragma unroll
        for (int j = 0; j < 4; ++j) acc[i][j] += av[i] * bv[j];
    }
    __syncthreads();
  }
  const float4 bb = *(const float4*)(bias + n0 + tx * 4);
#pragma unroll
  for (int i = 0; i < 8; ++i) {
    const int m = m0 + ty * 8 + i;
    float4 v;
    v.x = fmaxf(acc[i][0] + bb.x, 0.f);
    v.y = fmaxf(acc[i][1] + bb.y, 0.f);
    v.z = fmaxf(acc[i][2] + bb.z, 0.f);
    v.w = fmaxf(acc[i][3] + bb.w, 0.f);
    *(float4*)(Y + m * N + n0 + tx * 4) = v;
  }
}

// ------- gemm2 + L2 row-normalize ------------------------------------------
__global__ __launch_bounds__(256) void gemm2_norm_kernel(
    const float* __restrict__ Y1, const float* __restrict__ W2,
    const float* __restrict__ b2, float* __restrict__ F, int K, int C4) {
  __shared__ float Ys[16 * 516];
  __shared__ float ys2[16][129];
  __shared__ float scl[16];
  const int tid = threadIdx.x;
  const int row0 = blockIdx.x * 16;
  const int ldy = K + 4;
  for (int e = tid * 4; e < 16 * K; e += 1024) {
    int r = e / K, k = e - r * K;
    *(float4*)(&Ys[r * ldy + k]) = *(const float4*)(Y1 + (row0 + r) * K + k);
  }
  __syncthreads();
  const int r = tid & 15;
  const int jg = tid >> 4;
  const float* ysr = &Ys[r * ldy];
  for (int j0 = jg * 4; j0 < C4; j0 += 64) {
    float a0 = b2[j0], a1 = b2[j0 + 1], a2 = b2[j0 + 2], a3 = b2[j0 + 3];
    const float* w0 = W2 + (j0 + 0) * K;
    const float* w1 = W2 + (j0 + 1) * K;
    const float* w2 = W2 + (j0 + 2) * K;
    const float* w3 = W2 + (j0 + 3) * K;
    for (int k = 0; k < K; k += 4) {
      float4 y = *(const float4*)(ysr + k);
      float4 v0 = *(const float4*)(w0 + k);
      float4 v1 = *(const float4*)(w1 + k);
      float4 v2 = *(const float4*)(w2 + k);
      float4 v3 = *(const float4*)(w3 + k);
      a0 += y.x * v0.x + y.y * v0.y + y.z * v0.z + y.w * v0.w;
      a1 += y.x * v1.x + y.y * v1.y + y.z * v1.z + y.w * v1.w;
      a2 += y.x * v2.x + y.y * v2.y + y.z * v2.z + y.w * v2.w;
      a3 += y.x * v3.x + y.y * v3.y + y.z * v3.z + y.w * v3.w;
    }
    ys2[r][j0 + 0] = a0; ys2[r][j0 + 1] = a1;
    ys2[r][j0 + 2] = a2; ys2[r][j0 + 3] = a3;
  }
  __syncthreads();
  if (tid < 16) {
    float sum = 0.f;
    for (int j = 0; j < C4; ++j) { float v = ys2[tid][j]; sum += v * v; }
    scl[tid] = 1.f / (sqrtf(sum) + 1e-7f);
  }
  __syncthreads();
  for (int e = tid; e < 16 * C4; e += 256) {
    int rr = e / C4, j = e - rr * C4;
    F[(row0 + rr) * C4 + j] = ys2[rr][j] * scl[rr];
  }
}

// ---------------- NCE Gram GEMM: 64x64 tile, fused exp + diagonal -----------
// A = Fq rows (s), B = Fk rows (t), both [*][C4] (NT). k-major LDS tiles,
// float4 fragment reads (2x ds_read_b128 per 16 FMA). Accumulates
// sum_t!=s exp(d/tau - 1/tau) into rowsum via atomics; pos dot into posD.
__global__ __launch_bounds__(256) void nce_gemm_kernel(
    const float* __restrict__ Fq, const float* __restrict__ Fk,
    float* __restrict__ rowsum, float* __restrict__ posD,
    int C4, float invtau) {
  __shared__ float As[16][64];
  __shared__ float Bs[16][64];
  __shared__ float rsS[64];
  const int tid = threadIdx.x;
  const int b = blockIdx.z;
  const int s0 = blockIdx.x * 64;
  const int t0 = blockIdx.y * 64;
  const int tx = tid & 15;        // col group (4 cols)
  const int ty = tid >> 4;        // row group (4 rows)
  const int lr = tid >> 2;        // 0..63 load row
  const int lc = (tid & 3) * 4;   // 0,4,8,12 load k

  float acc[4][4];
#pragma unroll
  for (int i = 0; i < 4; ++i)
#pragma unroll
    for (int j = 0; j < 4; ++j) acc[i][j] = 0.f;

  const float* Abase = Fq + (size_t)(b * SS + s0) * C4;
  const float* Bbase = Fk + (size_t)(b * SS + t0) * C4;

  for (int k0 = 0; k0 < C4; k0 += 16) {
    float4 a0 = *(const float4*)(Abase + lr * C4 + k0 + lc);
    float4 b0 = *(const float4*)(Bbase + lr * C4 + k0 + lc);
    As[lc + 0][lr] = a0.x; As[lc + 1][lr] = a0.y;
    As[lc + 2][lr] = a0.z; As[lc + 3][lr] = a0.w;
    Bs[lc + 0][lr] = b0.x; Bs[lc + 1][lr] = b0.y;
    Bs[lc + 2][lr] = b0.z; Bs[lc + 3][lr] = b0.w;
    __syncthreads();
#pragma unroll
    for (int kk = 0; kk < 16; ++kk) {
      float4 av = *(const float4*)(&As[kk][ty * 4]);
      float4 bv = *(const float4*)(&Bs[kk][tx * 4]);
      float a[4] = {av.x, av.y, av.z, av.w};
      float bb[4] = {bv.x, bv.y, bv.z, bv.w};
#pragma unroll
      for (int i = 0; i < 4; ++i)
#pragma unroll
        for (int j = 0; j < 4; ++j) acc[i][j] += a[i] * bb[j];
    }
    __syncthreads();
  }

  if (tid < 64) rsS[tid] = 0.f;
  __syncthreads();
  float rs[4] = {0.f, 0.f, 0.f, 0.f};
#pragma unroll
  for (int i = 0; i < 4; ++i) {
    const int s = s0 + ty * 4 + i;
#pragma unroll
    for (int j = 0; j < 4; ++j) {
      const int t = t0 + tx * 4 + j;
      const float d = acc[i][j];
      if (t == s) posD[b * SS + s] = d;
      else rs[i] += __expf(d * invtau - invtau);
    }
  }
#pragma unroll
  for (int i = 0; i < 4; ++i) atomicAdd(&rsS[ty * 4 + i], rs[i]);
  __syncthreads();
  if (tid < 64) atomicAdd(&rowsum[b * SS + s0 + tid], rsS[tid]);
}

// ---------------- finalize: mean of (LSE - l_pos) over all rows -------------
__global__ __launch_bounds__(256) void nce_finalize_kernel(
    const float* __restrict__ rowsum, const float* __restrict__ posD,
    float* __restrict__ loss, float invtau, float scale) {
  __shared__ float red[4];
  const int idx = blockIdx.x * 256 + threadIdx.x;
  float v = 0.f;
  if (idx < MM) {
    const float p = posD[idx];
    const float lse = logf(rowsum[idx] + __expf(p * invtau - invtau)) + invtau;
    v = lse - p * invtau;
  }
#pragma unroll
  for (int off = 32; off > 0; off >>= 1) v += __shfl_down(v, off, 64);
  const int lane = threadIdx.x & 63;
  const int w = threadIdx.x >> 6;
  if (lane == 0) red[w] = v;
  __syncthreads();
  if (threadIdx.x == 0) {
    float s = red[0] + red[1] + red[2] + red[3];
    atomicAdd(loss, s * scale);
  }
}

extern "C" void kernel_launch(void* const* d_in, const int* in_sizes, int n_in,
                              void* d_out, int out_size, void* d_ws, size_t ws_size,
                              hipStream_t stream) {
  const int Cs[4] = {64, 128, 256, 512};
  const int Hs[4] = {256, 128, 64, 32};
  float* ws = (float*)d_ws;
  float* ft = ws;                          // 4096*512
  float* y1 = ws + MM * 512;               // 4096*512
  float* Fq = ws + 2 * MM * 512;           // 4096*128
  float* Fk = Fq + MM * 128;
  // rowsum/posD reuse the ft region (dead between last gemm1 read and next
  // layer's gather; stream order makes this safe).
  float* rowsum = ft;
  float* posD = ft + MM;
  float* out = (float*)d_out;

  hipLaunchKernelGGL(zero_kernel, dim3(1), dim3(1), 0, stream, out);

  for (int l = 0; l < 4; ++l) {
    const float* fq = (const float*)d_in[7 * l + 0];
    const float* fk = (const float*)d_in[7 * l + 1];
    const int* sid  = (const int*)d_in[7 * l + 2];
    const float* w1 = (const float*)d_in[7 * l + 3];
    const float* b1 = (const float*)d_in[7 * l + 4];
    const float* w2 = (const float*)d_in[7 * l + 5];
    const float* b2 = (const float*)d_in[7 * l + 6];
    const int C = Cs[l], H = Hs[l], C4 = C / 4;
    const int gblk = C < 256 ? C : 256;

    for (int side = 0; side < 2; ++side) {
      const float* feat = side ? fk : fq;
      float* F = side ? Fk : Fq;
      hipLaunchKernelGGL(gather_kernel, dim3(MM), dim3(gblk), 0, stream,
                         feat, sid, ft, C, H);
      hipLaunchKernelGGL(gemm1_relu_kernel, dim3(MM / 128, C / 64), dim3(256),
                         0, stream, ft, w1, b1, y1, C);
      hipLaunchKernelGGL(gemm2_norm_kernel, dim3(MM / 16), dim3(256), 0, stream,
                         y1, w2, b2, F, C, C4);
    }
    hipLaunchKernelGGL(zero_rowsum_kernel, dim3(MM / 256), dim3(256), 0, stream,
                       rowsum);
    hipLaunchKernelGGL(nce_gemm_kernel, dim3(SS / 64, SS / 64, BATCH), dim3(256),
                       0, stream, Fq, Fk, rowsum, posD, C4, 1.0f / 0.07f);
    hipLaunchKernelGGL(nce_finalize_kernel, dim3(MM / 256), dim3(256), 0, stream,
                       rowsum, posD, out, 1.0f / 0.07f, 1.0f / (float)MM);
  }
}

// Round 3
// 593.661 us; speedup vs baseline: 1.9444x; 1.4295x over previous
//
#include <hip/hip_runtime.h>
#include <math.h>

// PatchNCE loss via bf16 MFMA. B=8, S=512/batch, M2=8192 rows (q rows 0..4095,
// k rows 4096..8191). Per layer: cast W->bf16, gather (both sides) -> ftb(bf16),
// gemm1 MFMA+relu -> y1b(bf16), gemm2 MFMA + row L2-norm -> Fb(bf16, row stride
// RS=max(C4,32), zero-padded), NCE Gram MFMA + fused exp/LSE -> atomicAdd loss.
// MFMA 16x16x32 bf16: A/B frag = 8 contiguous k per lane (row=lane&15,
// k=(lane>>4)*8); C/D: col=lane&15, row=(lane>>4)*4+reg  [m89/m92-verified].

#define BATCH 8
#define SS    512
#define MM    4096
#define M2    8192

typedef __attribute__((ext_vector_type(8))) short bf16x8;
typedef __attribute__((ext_vector_type(4))) float f32x4;

static __device__ __forceinline__ short f2bf(float f) {
  union { float f; unsigned u; } v; v.f = f;
  unsigned r = (v.u + 0x7fffu + ((v.u >> 16) & 1u)) >> 16;   // RNE
  return (short)r;
}

__global__ void zero_kernel(float* __restrict__ out) { out[0] = 0.0f; }

__global__ void cast_w_kernel(const float* __restrict__ w1,
                              const float* __restrict__ w2,
                              short* __restrict__ w1b, short* __restrict__ w2b,
                              int n1, int n2) {
  int i = blockIdx.x * 256 + threadIdx.x;
  if (i < n1) w1b[i] = f2bf(w1[i]);
  else if (i < n1 + n2) w2b[i - n1] = f2bf(w2[i - n1]);
}

// gather both sides: row 0..4095 = q, 4096..8191 = k
__global__ void gather_kernel(const float* __restrict__ fq,
                              const float* __restrict__ fk,
                              const int* __restrict__ sid,
                              short* __restrict__ ftb, int C, int H) {
  const int row = blockIdx.x;
  const int r = row & (MM - 1);
  const float* feat = (row >= MM) ? fk : fq;
  const int b = r >> 9;
  const int s = (r >> 3) & 63;
  const int n = r & 7;
  const int idx = n < 4 ? n : n + 1;       // skip center of 3x3
  const int dh = idx / 3, dw = idx % 3;
  const int sh = sid[2 * s], sw = sid[2 * s + 1];
  const int HW = H * H;
  const float* fb = feat + (size_t)b * C * HW;
  const int o1 = (sh + dh) * H + (sw + dw);
  const int o2 = (sh + 1) * H + (sw + 1);
  for (int ch = threadIdx.x; ch < C; ch += blockDim.x) {
    ftb[(size_t)row * C + ch] = f2bf(fb[ch * HW + o1] - fb[ch * HW + o2]);
  }
}

// ---- gemm1: Y = relu(A @ W^T + b1), A: M2 x C (bf16), W: C x C (bf16) ------
// block 256 = 4 waves (2m x 2n), wave tile 64x32, direct-global MFMA frags.
__global__ __launch_bounds__(256) void gemm1_kernel(
    const short* __restrict__ A, const short* __restrict__ W,
    const float* __restrict__ bias, short* __restrict__ Y, int C) {
  const int tid = threadIdx.x;
  const int lane = tid & 63;
  const int w = tid >> 6;
  const int m0 = blockIdx.x * 128 + (w >> 1) * 64;
  const int n0 = blockIdx.y * 64 + (w & 1) * 32;
  const int l16 = lane & 15;
  const int q8 = (lane >> 4) * 8;
  f32x4 acc[4][2];
#pragma unroll
  for (int i = 0; i < 4; ++i)
#pragma unroll
    for (int j = 0; j < 2; ++j) acc[i][j] = (f32x4)(0.f);

  const short* Ap = A + (size_t)(m0 + l16) * C + q8;
  const short* Wp = W + (size_t)(n0 + l16) * C + q8;
  for (int k0 = 0; k0 < C; k0 += 32) {
    bf16x8 a[4], b[2];
#pragma unroll
    for (int mi = 0; mi < 4; ++mi)
      a[mi] = *(const bf16x8*)(Ap + (size_t)mi * 16 * C + k0);
#pragma unroll
    for (int ni = 0; ni < 2; ++ni)
      b[ni] = *(const bf16x8*)(Wp + (size_t)ni * 16 * C + k0);
#pragma unroll
    for (int mi = 0; mi < 4; ++mi)
#pragma unroll
      for (int ni = 0; ni < 2; ++ni)
        acc[mi][ni] = __builtin_amdgcn_mfma_f32_16x16x32_bf16(
            a[mi], b[ni], acc[mi][ni], 0, 0, 0);
  }
  const int rq = (lane >> 4) * 4;
#pragma unroll
  for (int ni = 0; ni < 2; ++ni) {
    const int n = n0 + ni * 16 + l16;
    const float bb = bias[n];
#pragma unroll
    for (int mi = 0; mi < 4; ++mi)
#pragma unroll
      for (int r = 0; r < 4; ++r) {
        const int m = m0 + mi * 16 + rq + r;
        Y[(size_t)m * C + n] = f2bf(fmaxf(acc[mi][ni][r] + bb, 0.f));
      }
  }
}

// ---- gemm2 + L2 row-normalize: F = normalize(Y @ W2^T + b2) ----------------
// block 256 = 4 waves, each wave 16 rows x full C4 (NF frags); butterfly
// sum-of-squares across the 16 col-lanes; store bf16 at row stride RS.
template <int NF>
__global__ __launch_bounds__(256) void gemm2_norm_kernel(
    const short* __restrict__ A, const short* __restrict__ W,
    const float* __restrict__ b2, short* __restrict__ F, int C, int RS) {
  const int tid = threadIdx.x;
  const int lane = tid & 63;
  const int w = tid >> 6;
  const int m0 = blockIdx.x * 64 + w * 16;
  const int l16 = lane & 15;
  const int q8 = (lane >> 4) * 8;
  f32x4 acc[NF];
#pragma unroll
  for (int f = 0; f < NF; ++f) acc[f] = (f32x4)(0.f);
  const short* Ap = A + (size_t)(m0 + l16) * C + q8;
  const short* Wp = W + (size_t)l16 * C + q8;
  for (int k0 = 0; k0 < C; k0 += 32) {
    bf16x8 a = *(const bf16x8*)(Ap + k0);
#pragma unroll
    for (int f = 0; f < NF; ++f) {
      bf16x8 b = *(const bf16x8*)(Wp + (size_t)f * 16 * C + k0);
      acc[f] = __builtin_amdgcn_mfma_f32_16x16x32_bf16(a, b, acc[f], 0, 0, 0);
    }
  }
  const int rq = (lane >> 4) * 4;
  float ss[4] = {0.f, 0.f, 0.f, 0.f};
#pragma unroll
  for (int f = 0; f < NF; ++f) {
    const float bb = b2[f * 16 + l16];
#pragma unroll
    for (int r = 0; r < 4; ++r) {
      acc[f][r] += bb;
      ss[r] += acc[f][r] * acc[f][r];
    }
  }
#pragma unroll
  for (int m = 1; m <= 8; m <<= 1)
#pragma unroll
    for (int r = 0; r < 4; ++r) ss[r] += __shfl_xor(ss[r], m, 64);
  float scl[4];
#pragma unroll
  for (int r = 0; r < 4; ++r) scl[r] = 1.f / (sqrtf(ss[r]) + 1e-7f);
#pragma unroll
  for (int f = 0; f < NF; ++f)
#pragma unroll
    for (int r = 0; r < 4; ++r) {
      const int row = m0 + rq + r;
      F[(size_t)row * RS + f * 16 + l16] = f2bf(acc[f][r] * scl[r]);
    }
  if (NF == 1) {  // C4==16 < MFMA K: zero-pad cols 16..31
#pragma unroll
    for (int r = 0; r < 4; ++r)
      F[(size_t)(m0 + rq + r) * RS + 16 + l16] = 0;
  }
}

// ---- NCE: Gram MFMA (64 s-rows/block x all 512 t) + fused exp/LSE ----------
__global__ __launch_bounds__(256) void nce_kernel(
    const short* __restrict__ F, float* __restrict__ loss,
    int RS, float invtau, float scale) {
  const int tid = threadIdx.x;
  const int lane = tid & 63;
  const int w = tid >> 6;
  const int b = blockIdx.y;
  const int s0 = blockIdx.x * 64 + w * 16;
  const int l16 = lane & 15;
  const int q8 = (lane >> 4) * 8;
  f32x4 acc[32];
#pragma unroll
  for (int f = 0; f < 32; ++f) acc[f] = (f32x4)(0.f);
  const short* Fq = F + (size_t)(b * SS + s0 + l16) * RS + q8;
  const short* Fk = F + (size_t)(MM + b * SS + l16) * RS + q8;
  for (int k0 = 0; k0 < RS; k0 += 32) {
    bf16x8 a = *(const bf16x8*)(Fq + k0);
#pragma unroll
    for (int f = 0; f < 32; ++f) {
      bf16x8 bb = *(const bf16x8*)(Fk + (size_t)f * 16 * RS + k0);
      acc[f] = __builtin_amdgcn_mfma_f32_16x16x32_bf16(a, bb, acc[f], 0, 0, 0);
    }
  }
  const int rq = (lane >> 4) * 4;
  float rs[4] = {0.f, 0.f, 0.f, 0.f};
  float pos[4] = {0.f, 0.f, 0.f, 0.f};
#pragma unroll
  for (int f = 0; f < 32; ++f) {
    const int t = f * 16 + l16;
#pragma unroll
    for (int r = 0; r < 4; ++r) {
      const int s = s0 + rq + r;
      const float d = acc[f][r];
      if (t == s) pos[r] += d;
      else rs[r] += __expf((d - 1.f) * invtau);
    }
  }
#pragma unroll
  for (int m = 1; m <= 8; m <<= 1)
#pragma unroll
    for (int r = 0; r < 4; ++r) {
      rs[r] += __shfl_xor(rs[r], m, 64);
      pos[r] += __shfl_xor(pos[r], m, 64);
    }
  if (l16 == 0) {
    float part = 0.f;
#pragma unroll
    for (int r = 0; r < 4; ++r) {
      const float p = pos[r];
      part += logf(rs[r] + __expf((p - 1.f) * invtau)) + invtau - p * invtau;
    }
    atomicAdd(loss, part * scale);
  }
}

extern "C" void kernel_launch(void* const* d_in, const int* in_sizes, int n_in,
                              void* d_out, int out_size, void* d_ws, size_t ws_size,
                              hipStream_t stream) {
  const int Cs[4] = {64, 128, 256, 512};
  const int Hs[4] = {256, 128, 64, 32};
  short* w1b = (short*)d_ws;                 // 262144
  short* w2b = w1b + 262144;                 // 65536
  short* ftb = w2b + 65536;                  // M2*512
  short* y1b = ftb + (size_t)M2 * 512;       // M2*512
  short* Fb  = y1b + (size_t)M2 * 512;       // M2*128
  float* out = (float*)d_out;

  zero_kernel<<<1, 1, 0, stream>>>(out);

  for (int l = 0; l < 4; ++l) {
    const float* fq = (const float*)d_in[7 * l + 0];
    const float* fk = (const float*)d_in[7 * l + 1];
    const int* sid  = (const int*)d_in[7 * l + 2];
    const float* w1 = (const float*)d_in[7 * l + 3];
    const float* b1 = (const float*)d_in[7 * l + 4];
    const float* w2 = (const float*)d_in[7 * l + 5];
    const float* b2 = (const float*)d_in[7 * l + 6];
    const int C = Cs[l], H = Hs[l], C4 = C / 4;
    const int RS = C4 < 32 ? 32 : C4;
    const int n1 = C * C, n2 = C4 * C;

    cast_w_kernel<<<(n1 + n2 + 255) / 256, 256, 0, stream>>>(
        w1, w2, w1b, w2b, n1, n2);
    gather_kernel<<<M2, C < 256 ? C : 256, 0, stream>>>(fq, fk, sid, ftb, C, H);
    gemm1_kernel<<<dim3(M2 / 128, C / 64), 256, 0, stream>>>(
        ftb, w1b, b1, y1b, C);
    switch (C4 >> 4) {
      case 1: gemm2_norm_kernel<1><<<M2 / 64, 256, 0, stream>>>(
                  y1b, w2b, b2, Fb, C, RS); break;
      case 2: gemm2_norm_kernel<2><<<M2 / 64, 256, 0, stream>>>(
                  y1b, w2b, b2, Fb, C, RS); break;
      case 4: gemm2_norm_kernel<4><<<M2 / 64, 256, 0, stream>>>(
                  y1b, w2b, b2, Fb, C, RS); break;
      default: gemm2_norm_kernel<8><<<M2 / 64, 256, 0, stream>>>(
                  y1b, w2b, b2, Fb, C, RS); break;
    }
    nce_kernel<<<dim3(SS / 64, BATCH), 256, 0, stream>>>(
        Fb, out, RS, 1.0f / 0.07f, 1.0f / (float)MM);
  }
}

// Round 4
// 491.644 us; speedup vs baseline: 2.3479x; 1.2075x over previous
//
#include <hip/hip_runtime.h>
#include <math.h>

// PatchNCE loss via bf16 MFMA, fully layer-batched: 4 dispatches total.
// stageA: zero loss + cast W->bf16 + gather (both sides, all layers) -> ftb
// stageB: gemm1 MFMA + relu -> y1b        (all layers, flattened grid)
// stageC: gemm2 MFMA + row L2-norm -> Fb  (bf16, row stride RS=max(C4,32))
// stageD: NCE Gram MFMA + fused exp/LSE -> atomicAdd loss (1 atomic/block)
// MFMA 16x16x32 bf16: A/B frag: row=lane&15, k=(lane>>4)*8 (+8 contiguous);
// C/D: col=lane&15, row=(lane>>4)*4+reg.

#define BATCH 8
#define SS    512
#define MM    4096
#define M2    8192

typedef __attribute__((ext_vector_type(8))) short bf16x8;
typedef __attribute__((ext_vector_type(4))) float f32x4;

struct Args {
  const float* fq[4]; const float* fk[4]; const int* sid[4];
  const float* w1[4]; const float* b1[4]; const float* w2[4]; const float* b2[4];
  short* w1b[4]; short* w2b[4]; short* ftb[4]; short* y1b[4]; short* Fb[4];
  float* out;
};

static __device__ __forceinline__ short f2bf(float f) {
  union { float f; unsigned u; } v; v.f = f;
  unsigned r = (v.u + 0x7fffu + ((v.u >> 16) & 1u)) >> 16;   // RNE
  return (short)r;
}

// ---------------- stage A: zero + cast weights + gather ---------------------
// blocks 0..22527: gather (l0:4 rows/blk, l1:2, l2/l3:1); 22528..24227: cast.
__global__ __launch_bounds__(256) void stageA(Args A) {
  const int bx = blockIdx.x, tid = threadIdx.x;
  if (bx == 0 && tid == 0) A.out[0] = 0.0f;
  if (bx < 22528) {
    int l, r0;
    if (bx < 2048)       { l = 0; r0 = bx * 4; }
    else if (bx < 6144)  { l = 1; r0 = (bx - 2048) * 2; }
    else if (bx < 14336) { l = 2; r0 = bx - 6144; }
    else                 { l = 3; r0 = bx - 14336; }
    const int C = 64 << l, H = 256 >> l;
    int row, ch0;
    if (l == 0)      { row = r0 + (tid >> 6); ch0 = tid & 63; }
    else if (l == 1) { row = r0 + (tid >> 7); ch0 = tid & 127; }
    else             { row = r0; ch0 = tid; }
    const int r = row & (MM - 1);
    const float* feat = (row >= MM) ? A.fk[l] : A.fq[l];
    const int b = r >> 9, s = (r >> 3) & 63, n = r & 7;
    const int idx = n < 4 ? n : n + 1;          // skip center of 3x3
    const int dh = idx / 3, dw = idx % 3;
    const int sh = A.sid[l][2 * s], sw = A.sid[l][2 * s + 1];
    const int HW = H * H;
    const float* fb = feat + (size_t)b * C * HW;
    const int o1 = (sh + dh) * H + sw + dw;
    const int o2 = (sh + 1) * H + sw + 1;
    short* ft = A.ftb[l] + (size_t)row * C;
    const int step = C < 256 ? C : 256;
    for (int ch = ch0; ch < C; ch += step)
      ft[ch] = f2bf(fb[(size_t)ch * HW + o1] - fb[(size_t)ch * HW + o2]);
  } else {
    const int cb = bx - 22528;
    int l, base;
    if (cb < 20)       { l = 0; base = cb; }
    else if (cb < 100) { l = 1; base = cb - 20; }
    else if (cb < 420) { l = 2; base = cb - 100; }
    else               { l = 3; base = cb - 420; }
    const int C = 64 << l;
    const int n1 = C * C, n2 = C * (C >> 2);
    const int i = base * 256 + tid;
    if (i < n1) A.w1b[l][i] = f2bf(A.w1[l][i]);
    else if (i < n1 + n2) A.w2b[l][i - n1] = f2bf(A.w2[l][i - n1]);
  }
}

// ---------------- stage B: Y = relu(ft @ W1^T + b1), all layers -------------
// per layer (M2/128)x(C/64) tiles: 64,128,256,512 blocks (cum 64,192,448,960)
__global__ __launch_bounds__(256) void stageB(Args A) {
  const int bx = blockIdx.x, tid = threadIdx.x;
  int l, bl;
  if (bx < 64)       { l = 0; bl = bx; }
  else if (bx < 192) { l = 1; bl = bx - 64; }
  else if (bx < 448) { l = 2; bl = bx - 192; }
  else               { l = 3; bl = bx - 448; }
  const int C = 64 << l;
  const int lane = tid & 63, w = tid >> 6;
  const int m0 = (bl & 63) * 128 + (w >> 1) * 64;
  const int n0 = (bl >> 6) * 64 + (w & 1) * 32;
  const int l16 = lane & 15;
  const int q8 = (lane >> 4) * 8;
  f32x4 acc[4][2];
#pragma unroll
  for (int i = 0; i < 4; ++i)
#pragma unroll
    for (int j = 0; j < 2; ++j) acc[i][j] = (f32x4)(0.f);

  const short* Ap = A.ftb[l] + (size_t)(m0 + l16) * C + q8;
  const short* Wp = A.w1b[l] + (size_t)(n0 + l16) * C + q8;
  for (int k0 = 0; k0 < C; k0 += 32) {
    bf16x8 a[4], b[2];
#pragma unroll
    for (int mi = 0; mi < 4; ++mi)
      a[mi] = *(const bf16x8*)(Ap + (size_t)mi * 16 * C + k0);
#pragma unroll
    for (int ni = 0; ni < 2; ++ni)
      b[ni] = *(const bf16x8*)(Wp + (size_t)ni * 16 * C + k0);
#pragma unroll
    for (int mi = 0; mi < 4; ++mi)
#pragma unroll
      for (int ni = 0; ni < 2; ++ni)
        acc[mi][ni] = __builtin_amdgcn_mfma_f32_16x16x32_bf16(
            a[mi], b[ni], acc[mi][ni], 0, 0, 0);
  }
  const int rq = (lane >> 4) * 4;
  short* Y = A.y1b[l];
  const float* bias = A.b1[l];
#pragma unroll
  for (int ni = 0; ni < 2; ++ni) {
    const int n = n0 + ni * 16 + l16;
    const float bb = bias[n];
#pragma unroll
    for (int mi = 0; mi < 4; ++mi)
#pragma unroll
      for (int r = 0; r < 4; ++r) {
        const int m = m0 + mi * 16 + rq + r;
        Y[(size_t)m * C + n] = f2bf(fmaxf(acc[mi][ni][r] + bb, 0.f));
      }
  }
}

// ---------------- stage C: F = normalize(Y @ W2^T + b2), all layers ---------
template <int NF>
static __device__ __forceinline__ void g2body(
    const short* __restrict__ Yl, const short* __restrict__ Wl,
    const float* __restrict__ b2, short* __restrict__ F,
    int C, int RS, int m0, int lane) {
  const int l16 = lane & 15;
  const int q8 = (lane >> 4) * 8;
  f32x4 acc[NF];
#pragma unroll
  for (int f = 0; f < NF; ++f) acc[f] = (f32x4)(0.f);
  const short* Ap = Yl + (size_t)(m0 + l16) * C + q8;
  const short* Wp = Wl + (size_t)l16 * C + q8;
  for (int k0 = 0; k0 < C; k0 += 32) {
    bf16x8 a = *(const bf16x8*)(Ap + k0);
#pragma unroll
    for (int f = 0; f < NF; ++f) {
      bf16x8 b = *(const bf16x8*)(Wp + (size_t)f * 16 * C + k0);
      acc[f] = __builtin_amdgcn_mfma_f32_16x16x32_bf16(a, b, acc[f], 0, 0, 0);
    }
  }
  const int rq = (lane >> 4) * 4;
  float ss[4] = {0.f, 0.f, 0.f, 0.f};
#pragma unroll
  for (int f = 0; f < NF; ++f) {
    const float bb = b2[f * 16 + l16];
#pragma unroll
    for (int r = 0; r < 4; ++r) {
      acc[f][r] += bb;
      ss[r] += acc[f][r] * acc[f][r];
    }
  }
#pragma unroll
  for (int m = 1; m <= 8; m <<= 1)
#pragma unroll
    for (int r = 0; r < 4; ++r) ss[r] += __shfl_xor(ss[r], m, 64);
#pragma unroll
  for (int f = 0; f < NF; ++f)
#pragma unroll
    for (int r = 0; r < 4; ++r)
      F[(size_t)(m0 + rq + r) * RS + f * 16 + l16] =
          f2bf(acc[f][r] / (sqrtf(ss[r]) + 1e-7f));
  if (NF == 1) {  // C4==16 < RS==32: zero-pad cols 16..31
#pragma unroll
    for (int r = 0; r < 4; ++r)
      F[(size_t)(m0 + rq + r) * RS + 16 + l16] = 0;
  }
}

__global__ __launch_bounds__(256) void stageC(Args A) {
  const int bx = blockIdx.x, tid = threadIdx.x;
  const int l = bx >> 7, bl = bx & 127;
  const int C = 64 << l, C4 = C >> 2;
  const int RS = C4 < 32 ? 32 : C4;
  const int lane = tid & 63, w = tid >> 6;
  const int m0 = bl * 64 + w * 16;
  if (l == 0)      g2body<1>(A.y1b[0], A.w2b[0], A.b2[0], A.Fb[0], C, RS, m0, lane);
  else if (l == 1) g2body<2>(A.y1b[1], A.w2b[1], A.b2[1], A.Fb[1], C, RS, m0, lane);
  else if (l == 2) g2body<4>(A.y1b[2], A.w2b[2], A.b2[2], A.Fb[2], C, RS, m0, lane);
  else             g2body<8>(A.y1b[3], A.w2b[3], A.b2[3], A.Fb[3], C, RS, m0, lane);
}

// ---------------- stage D: NCE Gram + fused exp/LSE, all layers -------------
// block = 16 s-rows; 4 waves each cover 128 t's (8 frags); LDS cross-wave
// reduce; one atomicAdd per block. 256 blocks/layer, 1024 total.
__global__ __launch_bounds__(256) void stageD(Args A) {
  const int bx = blockIdx.x, tid = threadIdx.x;
  const int l = bx >> 8, rem = bx & 255;
  const int b = rem >> 5, sblk = rem & 31;
  const int C4 = (64 << l) >> 2;
  const int RS = C4 < 32 ? 32 : C4;
  const int lane = tid & 63, w = tid >> 6;
  const int l16 = lane & 15;
  const int q8 = (lane >> 4) * 8;
  const int rq = (lane >> 4) * 4;
  const int s0 = sblk * 16;
  const short* F = A.Fb[l];
  f32x4 acc[8];
#pragma unroll
  for (int f = 0; f < 8; ++f) acc[f] = (f32x4)(0.f);
  const short* Fqp = F + (size_t)(b * SS + s0 + l16) * RS + q8;
  const short* Fkp = F + (size_t)(MM + b * SS + w * 128 + l16) * RS + q8;
  for (int k0 = 0; k0 < RS; k0 += 32) {
    bf16x8 a = *(const bf16x8*)(Fqp + k0);
#pragma unroll
    for (int f = 0; f < 8; ++f) {
      bf16x8 bb = *(const bf16x8*)(Fkp + (size_t)f * 16 * RS + k0);
      acc[f] = __builtin_amdgcn_mfma_f32_16x16x32_bf16(a, bb, acc[f], 0, 0, 0);
    }
  }
  const float invtau = 1.0f / 0.07f;
  float rs[4] = {0.f, 0.f, 0.f, 0.f};
  float pos[4] = {0.f, 0.f, 0.f, 0.f};
#pragma unroll
  for (int f = 0; f < 8; ++f) {
    const int t = w * 128 + f * 16 + l16;
#pragma unroll
    for (int r = 0; r < 4; ++r) {
      const int s = s0 + rq + r;
      const float d = acc[f][r];
      if (t == s) pos[r] = d;
      else rs[r] += __expf((d - 1.f) * invtau);
    }
  }
#pragma unroll
  for (int m = 1; m <= 8; m <<= 1)
#pragma unroll
    for (int r = 0; r < 4; ++r) {
      rs[r] += __shfl_xor(rs[r], m, 64);
      pos[r] += __shfl_xor(pos[r], m, 64);
    }
  __shared__ float rsS[4][16];
  __shared__ float posS[16];
  const int wd = sblk >> 3;   // wave whose t-range contains the diagonal
  if (l16 == 0) {
#pragma unroll
    for (int r = 0; r < 4; ++r) rsS[w][rq + r] = rs[r];
    if (w == wd)
#pragma unroll
      for (int r = 0; r < 4; ++r) posS[rq + r] = pos[r];
  }
  __syncthreads();
  if (tid < 16) {
    const float tot = rsS[0][tid] + rsS[1][tid] + rsS[2][tid] + rsS[3][tid];
    const float p = posS[tid];
    float v = logf(tot + __expf((p - 1.f) * invtau)) + invtau - p * invtau;
#pragma unroll
    for (int m = 1; m <= 8; m <<= 1) v += __shfl_xor(v, m, 64);
    if (tid == 0) atomicAdd(A.out, v * (1.0f / (float)MM));
  }
}

extern "C" void kernel_launch(void* const* d_in, const int* in_sizes, int n_in,
                              void* d_out, int out_size, void* d_ws, size_t ws_size,
                              hipStream_t stream) {
  short* ws = (short*)d_ws;
  // static workspace offsets (in shorts), all 16B-aligned
  static const size_t w1o[4] = {0, 4096, 20480, 86016};
  static const size_t w2o[4] = {348160, 349184, 353280, 369664};
  static const size_t fto[4] = {435200, 959488, 2008064, 4105216};
  static const size_t y1o[4] = {8299520, 8823808, 9872384, 11969536};
  static const size_t Fbo[4] = {16163840, 16425984, 16688128, 17212416};
  Args A;
  for (int l = 0; l < 4; ++l) {
    A.fq[l] = (const float*)d_in[7 * l + 0];
    A.fk[l] = (const float*)d_in[7 * l + 1];
    A.sid[l] = (const int*)d_in[7 * l + 2];
    A.w1[l] = (const float*)d_in[7 * l + 3];
    A.b1[l] = (const float*)d_in[7 * l + 4];
    A.w2[l] = (const float*)d_in[7 * l + 5];
    A.b2[l] = (const float*)d_in[7 * l + 6];
    A.w1b[l] = ws + w1o[l];
    A.w2b[l] = ws + w2o[l];
    A.ftb[l] = ws + fto[l];
    A.y1b[l] = ws + y1o[l];
    A.Fb[l] = ws + Fbo[l];
  }
  A.out = (float*)d_out;

  stageA<<<24228, 256, 0, stream>>>(A);
  stageB<<<960, 256, 0, stream>>>(A);
  stageC<<<512, 256, 0, stream>>>(A);
  stageD<<<1024, 256, 0, stream>>>(A);
}

// Round 5
// 453.483 us; speedup vs baseline: 2.5455x; 1.0842x over previous
//
#include <hip/hip_runtime.h>
#include <math.h>

// PatchNCE loss via bf16 MFMA, fully layer-batched: 4 dispatches total.
// stageA: zero loss + cast W->bf16 + corner-tile gather (LDS-staged, dense
//         128B corner-row reads) -> ftb (bf16, row-major [row][C])
// stageB: gemm1 MFMA + relu -> y1b        (all layers, flattened grid)
// stageC: gemm2 MFMA + row L2-norm -> Fb  (bf16, row stride RS=max(C4,32))
// stageD: NCE Gram MFMA + fused exp/LSE -> atomicAdd loss (1 atomic/block)
// MFMA 16x16x32 bf16: A/B frag: row=lane&15, k=(lane>>4)*8 (+8 contiguous);
// C/D: col=lane&15, row=(lane>>4)*4+reg.

#define BATCH 8
#define SS    512
#define MM    4096
#define M2    8192

typedef __attribute__((ext_vector_type(8))) short bf16x8;
typedef __attribute__((ext_vector_type(4))) float f32x4;

struct Args {
  const float* fq[4]; const float* fk[4]; const int* sid[4];
  const float* w1[4]; const float* b1[4]; const float* w2[4]; const float* b2[4];
  short* w1b[4]; short* w2b[4]; short* ftb[4]; short* y1b[4]; short* Fb[4];
  float* out;
};

static __device__ __forceinline__ short f2bf(float f) {
  union { float f; unsigned u; } v; v.f = f;
  unsigned r = (v.u + 0x7fffu + ((v.u >> 16) & 1u)) >> 16;   // RNE
  return (short)r;
}
static __device__ __forceinline__ float bf2f(short s) {
  union { unsigned u; float f; } v;
  v.u = ((unsigned)(unsigned short)s) << 16;
  return v.f;
}

// ---------------- stage A: zero + cast weights + corner gather --------------
// blocks 0..1919: gather. block=(side,b,8ch tile): l0:128, l1:256, l2:512,
// l3:1024 (cum 128,384,896,1920). blocks 1920..3619: weight cast.
// All sampled pixels lie in the 32x32 corner (sid<30, +dh/dw<=2 -> idx<=31).
__global__ __launch_bounds__(256) void stageA(Args A) {
  const int bx = blockIdx.x, tid = threadIdx.x;
  if (bx < 1920) {
    int l, idx;
    if (bx < 128)      { l = 0; idx = bx; }
    else if (bx < 384) { l = 1; idx = bx - 128; }
    else if (bx < 896) { l = 2; idx = bx - 384; }
    else               { l = 3; idx = bx - 896; }
    const int C = 64 << l, H = 256 >> l, HW = H * H;
    const int tile = idx & ((C >> 3) - 1);          // C/8 tiles
    const int b = (idx >> (3 + l)) & 7;
    const int side = idx >> (6 + l);
    const int ch0 = tile * 8;
    const float* feat = side ? A.fk[l] : A.fq[l];

    __shared__ short cor[8 * 1032];                 // 8 ch, stride 1032 shorts
    __shared__ int sidS[128];
    if (tid < 128) sidS[tid] = A.sid[l][tid];

    // phase 1: dense corner-row loads, cast to bf16 in LDS
    const int ch = tid >> 5, i = tid & 31;          // 8 ch x 32 rows
    const float* src = feat + (size_t)(b * C + ch0 + ch) * HW + (size_t)i * H;
    short* dst = &cor[ch * 1032 + i * 32];
#pragma unroll
    for (int j = 0; j < 8; ++j) {
      float4 v = *(const float4*)(src + 4 * j);
      short4 s;
      s.x = f2bf(v.x); s.y = f2bf(v.y); s.z = f2bf(v.z); s.w = f2bf(v.w);
      *(short4*)(dst + 4 * j) = s;
    }
    __syncthreads();

    // phase 2: 512 rows x 8 ch from LDS
    const int ch2 = tid & 7, r0 = tid >> 3;         // r0: 0..31
    const short* corch = &cor[ch2 * 1032];
    short* ftl = A.ftb[l];
#pragma unroll 4
    for (int jj = 0; jj < 16; ++jj) {
      const int sr = r0 + jj * 32;                  // 0..511
      const int s = sr >> 3, n = sr & 7;
      const int id2 = n < 4 ? n : n + 1;            // skip center of 3x3
      const int dh = id2 / 3, dw = id2 % 3;
      const int sh = sidS[2 * s], sw = sidS[2 * s + 1];
      const int p1 = (sh + dh) * 32 + sw + dw;
      const int p2 = (sh + 1) * 32 + sw + 1;
      const float d = bf2f(corch[p1]) - bf2f(corch[p2]);
      const int row = side * MM + b * SS + sr;
      ftl[(size_t)row * C + ch0 + ch2] = f2bf(d);
    }
  } else {
    const int cb = bx - 1920;
    int l, base;
    if (cb < 20)       { l = 0; base = cb; }
    else if (cb < 100) { l = 1; base = cb - 20; }
    else if (cb < 420) { l = 2; base = cb - 100; }
    else               { l = 3; base = cb - 420; }
    if (cb == 0 && tid == 0) A.out[0] = 0.0f;
    const int C = 64 << l;
    const int n1 = C * C, n2 = C * (C >> 2);
    const int i = base * 256 + tid;
    if (i < n1) A.w1b[l][i] = f2bf(A.w1[l][i]);
    else if (i < n1 + n2) A.w2b[l][i - n1] = f2bf(A.w2[l][i - n1]);
  }
}

// ---------------- stage B: Y = relu(ft @ W1^T + b1), all layers -------------
// per layer (M2/128)x(C/64) tiles: 64,128,256,512 blocks (cum 64,192,448,960)
__global__ __launch_bounds__(256) void stageB(Args A) {
  const int bx = blockIdx.x, tid = threadIdx.x;
  int l, bl;
  if (bx < 64)       { l = 0; bl = bx; }
  else if (bx < 192) { l = 1; bl = bx - 64; }
  else if (bx < 448) { l = 2; bl = bx - 192; }
  else               { l = 3; bl = bx - 448; }
  const int C = 64 << l;
  const int lane = tid & 63, w = tid >> 6;
  const int m0 = (bl & 63) * 128 + (w >> 1) * 64;
  const int n0 = (bl >> 6) * 64 + (w & 1) * 32;
  const int l16 = lane & 15;
  const int q8 = (lane >> 4) * 8;
  f32x4 acc[4][2];
#pragma unroll
  for (int i = 0; i < 4; ++i)
#pragma unroll
    for (int j = 0; j < 2; ++j) acc[i][j] = (f32x4)(0.f);

  const short* Ap = A.ftb[l] + (size_t)(m0 + l16) * C + q8;
  const short* Wp = A.w1b[l] + (size_t)(n0 + l16) * C + q8;
  for (int k0 = 0; k0 < C; k0 += 32) {
    bf16x8 a[4], b[2];
#pragma unroll
    for (int mi = 0; mi < 4; ++mi)
      a[mi] = *(const bf16x8*)(Ap + (size_t)mi * 16 * C + k0);
#pragma unroll
    for (int ni = 0; ni < 2; ++ni)
      b[ni] = *(const bf16x8*)(Wp + (size_t)ni * 16 * C + k0);
#pragma unroll
    for (int mi = 0; mi < 4; ++mi)
#pragma unroll
      for (int ni = 0; ni < 2; ++ni)
        acc[mi][ni] = __builtin_amdgcn_mfma_f32_16x16x32_bf16(
            a[mi], b[ni], acc[mi][ni], 0, 0, 0);
  }
  const int rq = (lane >> 4) * 4;
  short* Y = A.y1b[l];
  const float* bias = A.b1[l];
#pragma unroll
  for (int ni = 0; ni < 2; ++ni) {
    const int n = n0 + ni * 16 + l16;
    const float bb = bias[n];
#pragma unroll
    for (int mi = 0; mi < 4; ++mi)
#pragma unroll
      for (int r = 0; r < 4; ++r) {
        const int m = m0 + mi * 16 + rq + r;
        Y[(size_t)m * C + n] = f2bf(fmaxf(acc[mi][ni][r] + bb, 0.f));
      }
  }
}

// ---------------- stage C: F = normalize(Y @ W2^T + b2), all layers ---------
template <int NF>
static __device__ __forceinline__ void g2body(
    const short* __restrict__ Yl, const short* __restrict__ Wl,
    const float* __restrict__ b2, short* __restrict__ F,
    int C, int RS, int m0, int lane) {
  const int l16 = lane & 15;
  const int q8 = (lane >> 4) * 8;
  f32x4 acc[NF];
#pragma unroll
  for (int f = 0; f < NF; ++f) acc[f] = (f32x4)(0.f);
  const short* Ap = Yl + (size_t)(m0 + l16) * C + q8;
  const short* Wp = Wl + (size_t)l16 * C + q8;
  for (int k0 = 0; k0 < C; k0 += 32) {
    bf16x8 a = *(const bf16x8*)(Ap + k0);
#pragma unroll
    for (int f = 0; f < NF; ++f) {
      bf16x8 b = *(const bf16x8*)(Wp + (size_t)f * 16 * C + k0);
      acc[f] = __builtin_amdgcn_mfma_f32_16x16x32_bf16(a, b, acc[f], 0, 0, 0);
    }
  }
  const int rq = (lane >> 4) * 4;
  float ss[4] = {0.f, 0.f, 0.f, 0.f};
#pragma unroll
  for (int f = 0; f < NF; ++f) {
    const float bb = b2[f * 16 + l16];
#pragma unroll
    for (int r = 0; r < 4; ++r) {
      acc[f][r] += bb;
      ss[r] += acc[f][r] * acc[f][r];
    }
  }
#pragma unroll
  for (int m = 1; m <= 8; m <<= 1)
#pragma unroll
    for (int r = 0; r < 4; ++r) ss[r] += __shfl_xor(ss[r], m, 64);
#pragma unroll
  for (int f = 0; f < NF; ++f)
#pragma unroll
    for (int r = 0; r < 4; ++r)
      F[(size_t)(m0 + rq + r) * RS + f * 16 + l16] =
          f2bf(acc[f][r] / (sqrtf(ss[r]) + 1e-7f));
  if (NF == 1) {  // C4==16 < RS==32: zero-pad cols 16..31
#pragma unroll
    for (int r = 0; r < 4; ++r)
      F[(size_t)(m0 + rq + r) * RS + 16 + l16] = 0;
  }
}

__global__ __launch_bounds__(256) void stageC(Args A) {
  const int bx = blockIdx.x, tid = threadIdx.x;
  const int l = bx >> 7, bl = bx & 127;
  const int C = 64 << l, C4 = C >> 2;
  const int RS = C4 < 32 ? 32 : C4;
  const int lane = tid & 63, w = tid >> 6;
  const int m0 = bl * 64 + w * 16;
  if (l == 0)      g2body<1>(A.y1b[0], A.w2b[0], A.b2[0], A.Fb[0], C, RS, m0, lane);
  else if (l == 1) g2body<2>(A.y1b[1], A.w2b[1], A.b2[1], A.Fb[1], C, RS, m0, lane);
  else if (l == 2) g2body<4>(A.y1b[2], A.w2b[2], A.b2[2], A.Fb[2], C, RS, m0, lane);
  else             g2body<8>(A.y1b[3], A.w2b[3], A.b2[3], A.Fb[3], C, RS, m0, lane);
}

// ---------------- stage D: NCE Gram + fused exp/LSE, all layers -------------
// block = 16 s-rows; 4 waves each cover 128 t's (8 frags); LDS cross-wave
// reduce; one atomicAdd per block. 256 blocks/layer, 1024 total.
__global__ __launch_bounds__(256) void stageD(Args A) {
  const int bx = blockIdx.x, tid = threadIdx.x;
  const int l = bx >> 8, rem = bx & 255;
  const int b = rem >> 5, sblk = rem & 31;
  const int C4 = (64 << l) >> 2;
  const int RS = C4 < 32 ? 32 : C4;
  const int lane = tid & 63, w = tid >> 6;
  const int l16 = lane & 15;
  const int q8 = (lane >> 4) * 8;
  const int rq = (lane >> 4) * 4;
  const int s0 = sblk * 16;
  const short* F = A.Fb[l];
  f32x4 acc[8];
#pragma unroll
  for (int f = 0; f < 8; ++f) acc[f] = (f32x4)(0.f);
  const short* Fqp = F + (size_t)(b * SS + s0 + l16) * RS + q8;
  const short* Fkp = F + (size_t)(MM + b * SS + w * 128 + l16) * RS + q8;
  for (int k0 = 0; k0 < RS; k0 += 32) {
    bf16x8 a = *(const bf16x8*)(Fqp + k0);
#pragma unroll
    for (int f = 0; f < 8; ++f) {
      bf16x8 bb = *(const bf16x8*)(Fkp + (size_t)f * 16 * RS + k0);
      acc[f] = __builtin_amdgcn_mfma_f32_16x16x32_bf16(a, bb, acc[f], 0, 0, 0);
    }
  }
  const float invtau = 1.0f / 0.07f;
  float rs[4] = {0.f, 0.f, 0.f, 0.f};
  float pos[4] = {0.f, 0.f, 0.f, 0.f};
#pragma unroll
  for (int f = 0; f < 8; ++f) {
    const int t = w * 128 + f * 16 + l16;
#pragma unroll
    for (int r = 0; r < 4; ++r) {
      const int s = s0 + rq + r;
      const float d = acc[f][r];
      if (t == s) pos[r] = d;
      else rs[r] += __expf((d - 1.f) * invtau);
    }
  }
#pragma unroll
  for (int m = 1; m <= 8; m <<= 1)
#pragma unroll
    for (int r = 0; r < 4; ++r) {
      rs[r] += __shfl_xor(rs[r], m, 64);
      pos[r] += __shfl_xor(pos[r], m, 64);
    }
  __shared__ float rsS[4][16];
  __shared__ float posS[16];
  const int wd = sblk >> 3;   // wave whose t-range contains the diagonal
  if (l16 == 0) {
#pragma unroll
    for (int r = 0; r < 4; ++r) rsS[w][rq + r] = rs[r];
    if (w == wd)
#pragma unroll
      for (int r = 0; r < 4; ++r) posS[rq + r] = pos[r];
  }
  __syncthreads();
  if (tid < 16) {
    const float tot = rsS[0][tid] + rsS[1][tid] + rsS[2][tid] + rsS[3][tid];
    const float p = posS[tid];
    float v = logf(tot + __expf((p - 1.f) * invtau)) + invtau - p * invtau;
#pragma unroll
    for (int m = 1; m <= 8; m <<= 1) v += __shfl_xor(v, m, 64);
    if (tid == 0) atomicAdd(A.out, v * (1.0f / (float)MM));
  }
}

extern "C" void kernel_launch(void* const* d_in, const int* in_sizes, int n_in,
                              void* d_out, int out_size, void* d_ws, size_t ws_size,
                              hipStream_t stream) {
  short* ws = (short*)d_ws;
  // static workspace offsets (in shorts), all 16B-aligned
  static const size_t w1o[4] = {0, 4096, 20480, 86016};
  static const size_t w2o[4] = {348160, 349184, 353280, 369664};
  static const size_t fto[4] = {435200, 959488, 2008064, 4105216};
  static const size_t y1o[4] = {8299520, 8823808, 9872384, 11969536};
  static const size_t Fbo[4] = {16163840, 16425984, 16688128, 17212416};
  Args A;
  for (int l = 0; l < 4; ++l) {
    A.fq[l] = (const float*)d_in[7 * l + 0];
    A.fk[l] = (const float*)d_in[7 * l + 1];
    A.sid[l] = (const int*)d_in[7 * l + 2];
    A.w1[l] = (const float*)d_in[7 * l + 3];
    A.b1[l] = (const float*)d_in[7 * l + 4];
    A.w2[l] = (const float*)d_in[7 * l + 5];
    A.b2[l] = (const float*)d_in[7 * l + 6];
    A.w1b[l] = ws + w1o[l];
    A.w2b[l] = ws + w2o[l];
    A.ftb[l] = ws + fto[l];
    A.y1b[l] = ws + y1o[l];
    A.Fb[l] = ws + Fbo[l];
  }
  A.out = (float*)d_out;

  stageA<<<3620, 256, 0, stream>>>(A);
  stageB<<<960, 256, 0, stream>>>(A);
  stageC<<<512, 256, 0, stream>>>(A);
  stageD<<<1024, 256, 0, stream>>>(A);
}